// Round 2
// baseline (11104.809 us; speedup 1.0000x reference)
//
#include <hip/hip_runtime.h>
#include <hip/hip_bf16.h>
#include <math.h>

#define NPRED 65536
#define NGT   128
#define NCLS  256
#define CAP   12288
#define SENT_I 0x7FFFFFFF

// ---------- numeric helpers (match reference op order; no FMA contraction) ----------

__device__ __forceinline__ float sigmoid_f32(float x) {
#pragma clang fp contract(off)
    double s = 1.0 / (1.0 + exp(-(double)x));
    return (float)s;
}

// monotone map f32 -> uint32 for atomicMax over signed floats
__device__ __forceinline__ unsigned f2u(float f) {
    unsigned u = __float_as_uint(f);
    return (u & 0x80000000u) ? ~u : (u | 0x80000000u);
}

__device__ __forceinline__ float giou3d(
    float pl0, float pl1, float pl2, float ph0, float ph1, float ph2, float pvol,
    float gl0, float gl1, float gl2, float gh0, float gh1, float gh2, float gvol)
{
#pragma clang fp contract(off)
    float c0 = fmaxf(fminf(ph0, gh0) - fmaxf(pl0, gl0), 0.0f);
    float c1 = fmaxf(fminf(ph1, gh1) - fmaxf(pl1, gl1), 0.0f);
    float c2 = fmaxf(fminf(ph2, gh2) - fmaxf(pl2, gl2), 0.0f);
    float overlap = (c0 * c1) * c2;
    float uni = fmaxf((pvol + gvol) - overlap, 1e-6f);
    float iou = overlap / uni;
    float e0 = fmaxf(fmaxf(ph0, gh0) - fminf(pl0, gl0), 0.0f);
    float e1 = fmaxf(fmaxf(ph1, gh1) - fminf(pl1, gl1), 0.0f);
    float e2 = fmaxf(fmaxf(ph2, gh2) - fminf(pl2, gl2), 0.0f);
    float enc = fmaxf((e0 * e1) * e2, 1e-6f);
    return iou - (enc - uni) / enc;
}

// ---------- kernels ----------

__global__ void k_init(int* ccnt, unsigned* cmax) {
    int t = threadIdx.x;
    if (t < NGT) { ccnt[t] = 0; cmax[t] = 0u; }
}

__global__ __launch_bounds__(256) void k_cost(
    const float* __restrict__ pc, const float* __restrict__ ps,
    const float* __restrict__ cls, const float* __restrict__ gc,
    const float* __restrict__ gs, const int* __restrict__ lab,
    float* __restrict__ costT, int* __restrict__ ccnt, unsigned* __restrict__ cmax,
    int* __restrict__ cidx, float* __restrict__ cval)
{
#pragma clang fp contract(off)
    __shared__ float gb[NGT][6];
    __shared__ float gvol[NGT];
    __shared__ int   glab[NGT];
    int tid = threadIdx.x;
    if (tid < NGT) {
        float c0 = gc[tid * 3 + 0], c1 = gc[tid * 3 + 1], c2 = gc[tid * 3 + 2];
        float s0 = gs[tid * 3 + 0], s1 = gs[tid * 3 + 1], s2 = gs[tid * 3 + 2];
        float l0 = c0 - s0 / 2.0f, l1 = c1 - s1 / 2.0f, l2 = c2 - s2 / 2.0f;
        float h0 = c0 + s0 / 2.0f, h1 = c1 + s1 / 2.0f, h2 = c2 + s2 / 2.0f;
        gb[tid][0] = l0; gb[tid][1] = l1; gb[tid][2] = l2;
        gb[tid][3] = h0; gb[tid][4] = h1; gb[tid][5] = h2;
        gvol[tid] = ((h0 - l0) * (h1 - l1)) * (h2 - l2);
        glab[tid] = lab[tid];
    }
    __syncthreads();

    int p = blockIdx.x * 256 + tid;
    float c0 = pc[p * 3 + 0], c1 = pc[p * 3 + 1], c2 = pc[p * 3 + 2];
    float s0 = ps[p * 3 + 0], s1 = ps[p * 3 + 1], s2 = ps[p * 3 + 2];
    float pl0 = c0 - s0 / 2.0f, pl1 = c1 - s1 / 2.0f, pl2 = c2 - s2 / 2.0f;
    float ph0 = c0 + s0 / 2.0f, ph1 = c1 + s1 / 2.0f, ph2 = c2 + s2 / 2.0f;
    float pvol = ((ph0 - pl0) * (ph1 - pl1)) * (ph2 - pl2);
    const float* crow = cls + (size_t)p * NCLS;

    for (int g = 0; g < NGT; ++g) {
        float gio = giou3d(pl0, pl1, pl2, ph0, ph1, ph2, pvol,
                           gb[g][0], gb[g][1], gb[g][2], gb[g][3], gb[g][4], gb[g][5], gvol[g]);
        // per-gt column max (order-independent)
        float m = gio;
        for (int off = 32; off; off >>= 1) m = fmaxf(m, __shfl_xor(m, off, 64));
        if ((tid & 63) == 0) atomicMax(&cmax[g], f2u(m));
        // total cost = (-sigmoid) + 2*(-giou); weight-0 terms add exactly 0.0
        float sg = sigmoid_f32(crow[glab[g]]);
        float tot = (-sg) + (2.0f * (-gio));
        costT[(size_t)g * NPRED + p] = tot;
        // candidate collection for dynamic assignment
        if (gio > 0.25f) {
            int slot = atomicAdd(&ccnt[g], 1);
            if (slot < CAP) {
                cidx[(size_t)g * CAP + slot] = p;
                cval[(size_t)g * CAP + slot] = gio;
            }
        }
    }
}

__global__ __launch_bounds__(128) void k_sort(const unsigned* __restrict__ cmax,
                                              int* __restrict__ order) {
    __shared__ unsigned m[NGT];
    int t = threadIdx.x;
    m[t] = cmax[t];
    __syncthreads();
    unsigned mt = m[t];
    int r = 0;
    for (int k = 0; k < NGT; ++k) {
        unsigned mk = m[k];
        if (mk < mt || (mk == mt && k < t)) r++;
    }
    order[r] = t;  // stable ascending argsort
}

__global__ __launch_bounds__(1024) void k_lsa(
    const float* __restrict__ costT,
    double* __restrict__ v, double* __restrict__ shortest,
    int* __restrict__ path, int* __restrict__ row4col,
    unsigned char* __restrict__ SC, unsigned char* __restrict__ used,
    int* __restrict__ out)
{
#pragma clang fp contract(off)
    __shared__ double u_l[NGT];
    __shared__ int    c4r[NGT];
    __shared__ int    SR[NGT + 1];
    __shared__ int    bi, bsink, nSR;
    __shared__ double bmin;
    __shared__ double wval[16];
    __shared__ int    widx[16];
    int tid = threadIdx.x;

    for (int j = tid; j < NPRED; j += 1024) { v[j] = 0.0; row4col[j] = -1; }
    if (tid < NGT) { u_l[tid] = 0.0; c4r[tid] = -1; }
    __syncthreads();

    for (int cur = 0; cur < NGT; ++cur) {
        for (int j = tid; j < NPRED; j += 1024) {
            shortest[j] = (double)INFINITY; path[j] = -1; SC[j] = 0;
        }
        if (tid == 0) { bi = cur; bsink = -1; bmin = 0.0; SR[0] = cur; nSR = 1; }
        __syncthreads();

        while (true) {
            int irow = bi;
            double mv = bmin;
            double ui = u_l[irow];
            const float* crow = costT + (size_t)irow * NPRED;
            double bestv = (double)INFINITY;
            int    bestj = SENT_I;
            for (int j = tid; j < NPRED; j += 1024) {
                if (!SC[j]) {
                    double s = shortest[j];
                    double r = ((mv + (double)crow[j]) - ui) - v[j];
                    if (r < s) { s = r; shortest[j] = r; path[j] = irow; }
                    if (s < bestv || (s == bestv && j < bestj)) { bestv = s; bestj = j; }
                }
            }
            // wave-level (val,idx) argmin, first-index tie-break
            for (int off = 32; off; off >>= 1) {
                double ov = __shfl_down(bestv, off, 64);
                int    oj = __shfl_down(bestj, off, 64);
                if (ov < bestv || (ov == bestv && oj < bestj)) { bestv = ov; bestj = oj; }
            }
            if ((tid & 63) == 0) { wval[tid >> 6] = bestv; widx[tid >> 6] = bestj; }
            __syncthreads();
            if (tid == 0) {
                double bv = wval[0]; int bj = widx[0];
                for (int w = 1; w < 16; ++w) {
                    double ov = wval[w]; int oj = widx[w];
                    if (ov < bv || (ov == bv && oj < bj)) { bv = ov; bj = oj; }
                }
                bmin = bv;
                SC[bj] = 1;
                int r = row4col[bj];
                if (r < 0) { bsink = bj; }
                else       { SR[nSR++] = r; bi = r; }
            }
            __syncthreads();
            if (bsink >= 0) break;
        }

        double mv = bmin;
        // dual update on v over SC'd columns
        for (int j = tid; j < NPRED; j += 1024)
            if (SC[j]) v[j] -= (mv - shortest[j]);
        if (tid == 0) {
            u_l[cur] += mv;
            for (int k = 1; k < nSR; ++k) {
                int i2 = SR[k];
                u_l[i2] += mv - shortest[c4r[i2]];
            }
            // augment along path
            int j = bsink;
            while (true) {
                int i2 = path[j];
                row4col[j] = i2;
                int nj = c4r[i2];
                c4r[i2] = j;
                j = nj;
                if (i2 == cur) break;
            }
        }
        __syncthreads();
    }

    for (int j = tid; j < NPRED; j += 1024) used[j] = (row4col[j] >= 0) ? 1 : 0;
    if (tid < NGT) {
        out[tid]        = c4r[tid];   // combined_preds[0:128] = pred_indices
        out[1408 + tid] = tid;        // combined_gts[0:128]   = arange
    }
}

__global__ __launch_bounds__(256) void k_dyn(
    const int* __restrict__ order, const int* __restrict__ ccnt,
    const int* __restrict__ cidx, const float* __restrict__ cval,
    unsigned char* __restrict__ used, int* __restrict__ out)
{
    __shared__ float mv[256 * 10];
    __shared__ int   mi[256 * 10];
    int tid = threadIdx.x;

    for (int k = 0; k < NGT; ++k) {
        int gt = order[k];
        int nc = ccnt[gt];
        if (nc > CAP) nc = CAP;

        float lv[10]; int li[10];
#pragma unroll
        for (int q = 0; q < 10; ++q) { lv[q] = -1e30f; li[q] = SENT_I; }

        for (int c = tid; c < nc; c += 256) {
            int p = cidx[gt * CAP + c];
            float vv = cval[gt * CAP + c];
            if (used[p]) continue;
            float cvv = vv; int cii = p;
#pragma unroll
            for (int q = 0; q < 10; ++q) {
                bool b = (cvv > lv[q]) || (cvv == lv[q] && cii < li[q]);
                float tv = b ? lv[q] : cvv; int ti = b ? li[q] : cii;
                if (b) { lv[q] = cvv; li[q] = cii; }
                cvv = tv; cii = ti;
            }
        }
#pragma unroll
        for (int q = 0; q < 10; ++q) { mv[tid * 10 + q] = lv[q]; mi[tid * 10 + q] = li[q]; }
        __syncthreads();

        for (int s = 128; s >= 1; s >>= 1) {
            if (tid < s) {
                int a = tid, b = tid + s;
                int ia = 0, ib = 0;
                float ov[10]; int oi[10];
#pragma unroll
                for (int q = 0; q < 10; ++q) {
                    float va = (ia < 10) ? mv[a * 10 + ia] : -1e30f;
                    int   xa = (ia < 10) ? mi[a * 10 + ia] : SENT_I;
                    float vb = (ib < 10) ? mv[b * 10 + ib] : -1e30f;
                    int   xb = (ib < 10) ? mi[b * 10 + ib] : SENT_I;
                    bool pa = (va > vb) || (va == vb && xa < xb);
                    if (pa) { ov[q] = va; oi[q] = xa; ia++; }
                    else    { ov[q] = vb; oi[q] = xb; ib++; }
                }
#pragma unroll
                for (int q = 0; q < 10; ++q) { mv[a * 10 + q] = ov[q]; mi[a * 10 + q] = oi[q]; }
            }
            __syncthreads();
        }

        if (tid == 0) {
            for (int q = 0; q < 10; ++q) {
                int p = mi[q];
                bool valid = (p != SENT_I);
                out[128 + k * 10 + q]        = valid ? p  : -1;
                out[1408 + 128 + k * 10 + q] = valid ? gt : -1;
                if (valid) used[p] = 1;
            }
        }
        __syncthreads();
    }
}

// ---------- launch ----------

extern "C" void kernel_launch(void* const* d_in, const int* in_sizes, int n_in,
                              void* d_out, int out_size, void* d_ws, size_t ws_size,
                              hipStream_t stream) {
    const float* pc  = (const float*)d_in[0];   // all_centers [65536,3]
    const float* ps  = (const float*)d_in[1];   // all_sizes   [65536,3]
    const float* cls = (const float*)d_in[2];   // all_cls     [65536,256]
    // d_in[3] all_objness: weight 0.0 -> exact no-op in the cost sum
    const float* gc  = (const float*)d_in[4];   // gt_centers  [128,3]
    const float* gs  = (const float*)d_in[5];   // gt_sizes    [128,3]
    const int*   lab = (const int*)d_in[6];     // gt_labels   [128]

    char* ws = (char*)d_ws;
    float*         costT    = (float*)(ws + 0);                      // 33,554,432 B
    double*        v        = (double*)(ws + 33554432);              //    524,288 B
    double*        shortest = (double*)(ws + 34078720);              //    524,288 B
    int*           path     = (int*)(ws + 34603008);                 //    262,144 B
    int*           row4col  = (int*)(ws + 34865152);                 //    262,144 B
    unsigned char* SC       = (unsigned char*)(ws + 35127296);       //     65,536 B
    unsigned char* used     = (unsigned char*)(ws + 35192832);       //     65,536 B
    int*           ccnt     = (int*)(ws + 35258368);                 //        512 B
    unsigned*      cmax     = (unsigned*)(ws + 35258880);            //        512 B
    int*           order    = (int*)(ws + 35259392);                 //        512 B
    int*           cidx     = (int*)(ws + 35259904);                 //  6,291,456 B
    float*         cval     = (float*)(ws + 35259904 + (size_t)NGT * CAP * 4); // 6,291,456 B

    int* out = (int*)d_out;

    hipLaunchKernelGGL(k_init, dim3(1), dim3(128), 0, stream, ccnt, cmax);
    hipLaunchKernelGGL(k_cost, dim3(NPRED / 256), dim3(256), 0, stream,
                       pc, ps, cls, gc, gs, lab, costT, ccnt, cmax, cidx, cval);
    hipLaunchKernelGGL(k_sort, dim3(1), dim3(128), 0, stream, cmax, order);
    hipLaunchKernelGGL(k_lsa, dim3(1), dim3(1024), 0, stream,
                       costT, v, shortest, path, row4col, SC, used, out);
    hipLaunchKernelGGL(k_dyn, dim3(1), dim3(256), 0, stream,
                       order, ccnt, cidx, cval, used, out);
}

// Round 4
// 2869.127 us; speedup vs baseline: 3.8704x; 3.8704x over previous
//
#include <hip/hip_runtime.h>
#include <hip/hip_bf16.h>
#include <math.h>

#define NPRED 65536
#define NGT   128
#define NCLS  256
#define CAP   12288
#define VCAP  160
#define SENT_I 0x7FFFFFFF

// ---------- numeric helpers (match reference op order; no FMA contraction) ----------

__device__ __forceinline__ float sigmoid_f32(float x) {
#pragma clang fp contract(off)
    double s = 1.0 / (1.0 + exp(-(double)x));
    return (float)s;
}

__device__ __forceinline__ unsigned f2u(float f) {
    unsigned u = __float_as_uint(f);
    return (u & 0x80000000u) ? ~u : (u | 0x80000000u);
}

__device__ __forceinline__ float giou3d(
    float pl0, float pl1, float pl2, float ph0, float ph1, float ph2, float pvol,
    float gl0, float gl1, float gl2, float gh0, float gh1, float gh2, float gvol)
{
#pragma clang fp contract(off)
    float c0 = fmaxf(fminf(ph0, gh0) - fmaxf(pl0, gl0), 0.0f);
    float c1 = fmaxf(fminf(ph1, gh1) - fmaxf(pl1, gl1), 0.0f);
    float c2 = fmaxf(fminf(ph2, gh2) - fmaxf(pl2, gl2), 0.0f);
    float overlap = (c0 * c1) * c2;
    float uni = fmaxf((pvol + gvol) - overlap, 1e-6f);
    float iou = overlap / uni;
    float e0 = fmaxf(fmaxf(ph0, gh0) - fminf(pl0, gl0), 0.0f);
    float e1 = fmaxf(fmaxf(ph1, gh1) - fminf(pl1, gl1), 0.0f);
    float e2 = fmaxf(fmaxf(ph2, gh2) - fminf(pl2, gl2), 0.0f);
    float enc = fmaxf((e0 * e1) * e2, 1e-6f);
    return iou - (enc - uni) / enc;
}

// ---------- kernels ----------

__global__ void k_init(int* ccnt, unsigned* cmax) {
    int t = threadIdx.x;
    if (t < NGT) { ccnt[t] = 0; cmax[t] = 0u; }
}

__global__ __launch_bounds__(256) void k_cost(
    const float* __restrict__ pc, const float* __restrict__ ps,
    const float* __restrict__ cls, const float* __restrict__ gc,
    const float* __restrict__ gs, const int* __restrict__ lab,
    float* __restrict__ costT, int* __restrict__ ccnt, unsigned* __restrict__ cmax,
    int* __restrict__ cidx, float* __restrict__ cval)
{
#pragma clang fp contract(off)
    __shared__ float gb[NGT][6];
    __shared__ float gvol[NGT];
    __shared__ int   glab[NGT];
    int tid = threadIdx.x;
    if (tid < NGT) {
        float c0 = gc[tid * 3 + 0], c1 = gc[tid * 3 + 1], c2 = gc[tid * 3 + 2];
        float s0 = gs[tid * 3 + 0], s1 = gs[tid * 3 + 1], s2 = gs[tid * 3 + 2];
        float l0 = c0 - s0 / 2.0f, l1 = c1 - s1 / 2.0f, l2 = c2 - s2 / 2.0f;
        float h0 = c0 + s0 / 2.0f, h1 = c1 + s1 / 2.0f, h2 = c2 + s2 / 2.0f;
        gb[tid][0] = l0; gb[tid][1] = l1; gb[tid][2] = l2;
        gb[tid][3] = h0; gb[tid][4] = h1; gb[tid][5] = h2;
        gvol[tid] = ((h0 - l0) * (h1 - l1)) * (h2 - l2);
        glab[tid] = lab[tid];
    }
    __syncthreads();

    int p = blockIdx.x * 256 + tid;
    float c0 = pc[p * 3 + 0], c1 = pc[p * 3 + 1], c2 = pc[p * 3 + 2];
    float s0 = ps[p * 3 + 0], s1 = ps[p * 3 + 1], s2 = ps[p * 3 + 2];
    float pl0 = c0 - s0 / 2.0f, pl1 = c1 - s1 / 2.0f, pl2 = c2 - s2 / 2.0f;
    float ph0 = c0 + s0 / 2.0f, ph1 = c1 + s1 / 2.0f, ph2 = c2 + s2 / 2.0f;
    float pvol = ((ph0 - pl0) * (ph1 - pl1)) * (ph2 - pl2);
    const float* crow = cls + (size_t)p * NCLS;

    for (int g = 0; g < NGT; ++g) {
        float gio = giou3d(pl0, pl1, pl2, ph0, ph1, ph2, pvol,
                           gb[g][0], gb[g][1], gb[g][2], gb[g][3], gb[g][4], gb[g][5], gvol[g]);
        float m = gio;
        for (int off = 32; off; off >>= 1) m = fmaxf(m, __shfl_xor(m, off, 64));
        if ((tid & 63) == 0) atomicMax(&cmax[g], f2u(m));
        float sg = sigmoid_f32(crow[glab[g]]);
        float tot = (-sg) + (2.0f * (-gio));
        costT[(size_t)g * NPRED + p] = tot;
        if (gio > 0.25f) {
            int slot = atomicAdd(&ccnt[g], 1);
            if (slot < CAP) {
                cidx[(size_t)g * CAP + slot] = p;
                cval[(size_t)g * CAP + slot] = gio;
            }
        }
    }
}

__global__ __launch_bounds__(128) void k_sort(const unsigned* __restrict__ cmax,
                                              int* __restrict__ order) {
    __shared__ unsigned m[NGT];
    int t = threadIdx.x;
    m[t] = cmax[t];
    __syncthreads();
    unsigned mt = m[t];
    int r = 0;
    for (int k = 0; k < NGT; ++k) {
        unsigned mk = m[k];
        if (mk < mt || (mk == mt && k < t)) r++;
    }
    order[r] = t;
}

// per-(row,segment) min of raw cost, lex (value, index); also zero inVmap/failFlag
// GRID: 128 rows * 512 segs = 65536 waves = 16384 blocks of 4 waves
__global__ __launch_bounds__(256) void k_segmin(
    const float* __restrict__ costT, float* __restrict__ segval, int* __restrict__ segidx,
    int* __restrict__ inVmap, int* __restrict__ failFlag)
{
    int gid = blockIdx.x * 256 + threadIdx.x;
    if (gid < NPRED) inVmap[gid] = 0;
    if (gid == 0) *failFlag = 0;
    int wave = blockIdx.x * 4 + (threadIdx.x >> 6);
    int lane = threadIdx.x & 63;
    int row = wave >> 9;   // [0,128)
    int seg = wave & 511;  // [0,512)
    const float* crow = costT + (size_t)row * NPRED;
    int j0 = seg * 128 + lane;
    float c0 = crow[j0], c1 = crow[j0 + 64];
    float bc; int bj;
    if (c1 < c0) { bc = c1; bj = j0 + 64; } else { bc = c0; bj = j0; }
    for (int off = 1; off < 64; off <<= 1) {
        float oc = __shfl_xor(bc, off, 64);
        int   oj = __shfl_xor(bj, off, 64);
        if (oc < bc || (oc == bc && oj < bj)) { bc = oc; bj = oj; }
    }
    if (lane == 0) { segval[row * 512 + seg] = bc; segidx[row * 512 + seg] = bj; }
}

// sparse JV LSA: V = ever-picked columns (<=128), LDS-resident; untouched columns
// served by per-(row,segment) cost minima. Bit-identical to the dense numpy JV.
__global__ __launch_bounds__(1024) void k_lsa_sparse(
    const float* __restrict__ costT,
    float* __restrict__ segval, int* __restrict__ segidx,
    int* __restrict__ inVmap, int* __restrict__ failFlag,
    unsigned char* __restrict__ used, int* __restrict__ out)
{
#pragma clang fp contract(off)
    __shared__ double u_l[NGT];
    __shared__ int    c4r[NGT];
    __shared__ int    colidV[VCAP];
    __shared__ double vV[VCAP], shortV[VCAP];
    __shared__ int    pathV[VCAP], r4cV[VCAP];
    __shared__ unsigned char SCV[VCAP];
    __shared__ int    SRr[VCAP];
    __shared__ double mvAt[VCAP];
    __shared__ double headv[VCAP];
    __shared__ int    headj[VCAP];
    __shared__ double wvr[2]; __shared__ int wjr[2]; __shared__ int wkr[2];
    __shared__ int sh_bi, sh_sink, sh_nSR, sh_nV, sh_fixcol, sh_fail;
    __shared__ double sh_mv;

    int tid = threadIdx.x;
    int lane = tid & 63, wav = tid >> 6;

    if (tid < NGT) { u_l[tid] = 0.0; c4r[tid] = -1; }
    if (tid == 0) { sh_nV = 0; sh_fixcol = -1; sh_fail = 0; }
    __syncthreads();

    for (int cur = 0; cur < NGT; ++cur) {
        // repair segment minima for the column that joined V at the end of last round
        int fixcol = sh_fixcol;  // register copy; tid0 resets it only after the barrier below
        if (fixcol >= 0) {
            int seg = fixcol >> 7, base = seg << 7;
            int r = tid >> 3, sub = tid & 7;  // 8 threads per row, 128 rows
            if (segidx[r * 512 + seg] == fixcol) {
                const float* crow = costT + (size_t)r * NPRED;
                float bc = INFINITY; int bj = SENT_I;
                for (int t = 0; t < 16; ++t) {
                    int j = base + sub * 16 + t;
                    if (inVmap[j] == 0) {
                        float c = crow[j];
                        if (c < bc || (c == bc && j < bj)) { bc = c; bj = j; }
                    }
                }
                for (int off = 1; off < 8; off <<= 1) {
                    float oc = __shfl_xor(bc, off, 64);
                    int   oj = __shfl_xor(bj, off, 64);
                    if (oc < bc || (oc == bc && oj < bj)) { bc = oc; bj = oj; }
                }
                if (sub == 0) { segval[r * 512 + seg] = bc; segidx[r * 512 + seg] = bj; }
            }
        }
        __syncthreads();  // all reads of sh_fixcol done; repair writes ordered
        // per-round reset
        if (tid < sh_nV) { shortV[tid] = INFINITY; pathV[tid] = -1; SCV[tid] = 0; }
        if (tid == 0) {
            sh_bi = cur; sh_sink = -1; sh_mv = 0.0;
            SRr[0] = cur; mvAt[0] = 0.0; sh_nSR = 1; sh_fixcol = -1;
        }
        __syncthreads();

        while (true) {
            int bi = sh_bi; double mv = sh_mv; int nV = sh_nV; int s = sh_nSR;
            double ui = u_l[bi];
            if (wav < 2) {
                // exact scan of V-members for the current row
                double bv = INFINITY; int bj = SENT_I, bk = -1;
                if (tid < nV && !SCV[tid]) {
                    double c = (double)costT[(size_t)bi * NPRED + colidV[tid]];
                    double r = ((mv + c) - ui) - vV[tid];
                    if (r < shortV[tid]) { shortV[tid] = r; pathV[tid] = bi; }
                    bv = shortV[tid]; bj = colidV[tid]; bk = tid;
                }
                for (int off = 1; off < 64; off <<= 1) {
                    double ov = __shfl_xor(bv, off, 64);
                    int    oj = __shfl_xor(bj, off, 64);
                    int    ok = __shfl_xor(bk, off, 64);
                    if (ov < bv || (ov == bv && oj < bj)) { bv = ov; bj = oj; bk = ok; }
                }
                if (lane == 0) { wvr[wav] = bv; wjr[wav] = bj; wkr[wav] = bk; }
            } else {
                // per-SR-row best untouched column from segment minima
                for (int p = wav - 2; p < s; p += 14) {
                    int r = SRr[p];
                    float bc = INFINITY; int bj = SENT_I;
                    for (int seg = lane; seg < 512; seg += 64) {
                        float c = segval[r * 512 + seg];
                        int   j = segidx[r * 512 + seg];
                        if (c < bc || (c == bc && j < bj)) { bc = c; bj = j; }
                    }
                    for (int off = 1; off < 64; off <<= 1) {
                        float oc = __shfl_xor(bc, off, 64);
                        int   oj = __shfl_xor(bj, off, 64);
                        if (oc < bc || (oc == bc && oj < bj)) { bc = oc; bj = oj; }
                    }
                    if (lane == 0) {
                        if (bj == SENT_I) { headv[p] = INFINITY; headj[p] = SENT_I; }
                        else { headv[p] = ((mvAt[p] + (double)bc) - u_l[r]); headj[p] = bj; }
                    }
                }
            }
            __syncthreads();
            if (tid == 0) {
                double bv = wvr[0]; int bj = wjr[0], bk = wkr[0];
                if (wvr[1] < bv || (wvr[1] == bv && wjr[1] < bj)) { bv = wvr[1]; bj = wjr[1]; bk = wkr[1]; }
                int pick_row = -1;
                for (int p = 0; p < s; ++p) {  // ascending => earliest SR row kept on exact tie
                    if (headv[p] < bv || (headv[p] == bv && headj[p] < bj)) {
                        bv = headv[p]; bj = headj[p]; bk = -1; pick_row = SRr[p];
                    }
                }
                sh_mv = bv;
                if (bk >= 0) {
                    // assigned V-member: extend alternating path
                    SCV[bk] = 1;
                    int nr = r4cV[bk];
                    SRr[s] = nr; mvAt[s] = bv; sh_nSR = s + 1; sh_bi = nr;
                } else {
                    // untouched column: always unassigned => sink; join V
                    int k2 = sh_nV;
                    if (k2 >= VCAP) { sh_fail = 1; }
                    else {
                        colidV[k2] = bj; vV[k2] = 0.0; shortV[k2] = bv;
                        pathV[k2] = pick_row; SCV[k2] = 1; r4cV[k2] = -1;
                        inVmap[bj] = k2 + 1;
                        sh_nV = k2 + 1;
                        sh_sink = bj; sh_fixcol = bj;
                    }
                }
            }
            __syncthreads();
            if (sh_sink >= 0 || sh_fail) break;
        }
        if (sh_fail) break;

        // round end: dual updates + augment
        double mvf = sh_mv;
        if (tid < sh_nV && SCV[tid]) vV[tid] -= (mvf - shortV[tid]);
        if (tid == 0) {
            u_l[cur] += mvf;
            int s = sh_nSR;
            for (int q = 1; q < s; ++q) {
                int i2 = SRr[q];
                int kk = inVmap[c4r[i2]] - 1;
                u_l[i2] += mvf - shortV[kk];
            }
            int j = sh_sink;
            while (true) {
                int kk = inVmap[j] - 1;
                int i2 = pathV[kk];
                r4cV[kk] = i2;
                int nj = c4r[i2];
                c4r[i2] = j;
                j = nj;
                if (i2 == cur) break;
            }
        }
        __syncthreads();
    }

    if (tid == 0 && sh_fail) *failFlag = 1;
    if (!sh_fail) {
        for (int j = tid; j < NPRED; j += 1024) used[j] = 0;
        __syncthreads();
        if (tid < NGT) {
            used[c4r[tid]] = 1;
            out[tid]        = c4r[tid];
            out[1408 + tid] = tid;
        }
    }
}

// dense fallback: only runs if k_lsa_sparse flagged overflow (should never happen)
__global__ __launch_bounds__(1024) void k_lsa_dense(
    const float* __restrict__ costT, const int* __restrict__ failFlag,
    double* __restrict__ v, double* __restrict__ shortest,
    int* __restrict__ path, int* __restrict__ row4col,
    unsigned char* __restrict__ SC, unsigned char* __restrict__ used,
    int* __restrict__ out)
{
#pragma clang fp contract(off)
    if (*failFlag == 0) return;
    __shared__ double u_l[NGT];
    __shared__ int    c4r[NGT];
    __shared__ int    SR[NGT + 1];
    __shared__ int    bi, bsink, nSR;
    __shared__ double bmin;
    __shared__ double wval[16];
    __shared__ int    widx[16];
    int tid = threadIdx.x;

    for (int j = tid; j < NPRED; j += 1024) { v[j] = 0.0; row4col[j] = -1; }
    if (tid < NGT) { u_l[tid] = 0.0; c4r[tid] = -1; }
    __syncthreads();

    for (int cur = 0; cur < NGT; ++cur) {
        for (int j = tid; j < NPRED; j += 1024) {
            shortest[j] = (double)INFINITY; path[j] = -1; SC[j] = 0;
        }
        if (tid == 0) { bi = cur; bsink = -1; bmin = 0.0; SR[0] = cur; nSR = 1; }
        __syncthreads();

        while (true) {
            int irow = bi;
            double mv = bmin;
            double ui = u_l[irow];
            const float* crow = costT + (size_t)irow * NPRED;
            double bestv = (double)INFINITY;
            int    bestj = SENT_I;
            for (int j = tid; j < NPRED; j += 1024) {
                if (!SC[j]) {
                    double s = shortest[j];
                    double r = ((mv + (double)crow[j]) - ui) - v[j];
                    if (r < s) { s = r; shortest[j] = r; path[j] = irow; }
                    if (s < bestv || (s == bestv && j < bestj)) { bestv = s; bestj = j; }
                }
            }
            for (int off = 32; off; off >>= 1) {
                double ov = __shfl_down(bestv, off, 64);
                int    oj = __shfl_down(bestj, off, 64);
                if (ov < bestv || (ov == bestv && oj < bestj)) { bestv = ov; bestj = oj; }
            }
            if ((tid & 63) == 0) { wval[tid >> 6] = bestv; widx[tid >> 6] = bestj; }
            __syncthreads();
            if (tid == 0) {
                double bv = wval[0]; int bj = widx[0];
                for (int w = 1; w < 16; ++w) {
                    double ov = wval[w]; int oj = widx[w];
                    if (ov < bv || (ov == bv && oj < bj)) { bv = ov; bj = oj; }
                }
                bmin = bv;
                SC[bj] = 1;
                int r = row4col[bj];
                if (r < 0) { bsink = bj; }
                else       { SR[nSR++] = r; bi = r; }
            }
            __syncthreads();
            if (bsink >= 0) break;
        }

        double mv = bmin;
        for (int j = tid; j < NPRED; j += 1024)
            if (SC[j]) v[j] -= (mv - shortest[j]);
        if (tid == 0) {
            u_l[cur] += mv;
            for (int k = 1; k < nSR; ++k) {
                int i2 = SR[k];
                u_l[i2] += mv - shortest[c4r[i2]];
            }
            int j = bsink;
            while (true) {
                int i2 = path[j];
                row4col[j] = i2;
                int nj = c4r[i2];
                c4r[i2] = j;
                j = nj;
                if (i2 == cur) break;
            }
        }
        __syncthreads();
    }

    for (int j = tid; j < NPRED; j += 1024) used[j] = (row4col[j] >= 0) ? 1 : 0;
    if (tid < NGT) {
        out[tid]        = c4r[tid];
        out[1408 + tid] = tid;
    }
}

__global__ __launch_bounds__(256) void k_dyn(
    const int* __restrict__ order, const int* __restrict__ ccnt,
    const int* __restrict__ cidx, const float* __restrict__ cval,
    unsigned char* __restrict__ used, int* __restrict__ out)
{
    __shared__ float mv[256 * 10];
    __shared__ int   mi[256 * 10];
    int tid = threadIdx.x;

    for (int k = 0; k < NGT; ++k) {
        int gt = order[k];
        int nc = ccnt[gt];
        if (nc > CAP) nc = CAP;

        float lv[10]; int li[10];
#pragma unroll
        for (int q = 0; q < 10; ++q) { lv[q] = -1e30f; li[q] = SENT_I; }

        for (int c = tid; c < nc; c += 256) {
            int p = cidx[gt * CAP + c];
            float vv = cval[gt * CAP + c];
            if (used[p]) continue;
            float cvv = vv; int cii = p;
#pragma unroll
            for (int q = 0; q < 10; ++q) {
                bool b = (cvv > lv[q]) || (cvv == lv[q] && cii < li[q]);
                float tv = b ? lv[q] : cvv; int ti = b ? li[q] : cii;
                if (b) { lv[q] = cvv; li[q] = cii; }
                cvv = tv; cii = ti;
            }
        }
#pragma unroll
        for (int q = 0; q < 10; ++q) { mv[tid * 10 + q] = lv[q]; mi[tid * 10 + q] = li[q]; }
        __syncthreads();

        for (int s = 128; s >= 1; s >>= 1) {
            if (tid < s) {
                int a = tid, b = tid + s;
                int ia = 0, ib = 0;
                float ov[10]; int oi[10];
#pragma unroll
                for (int q = 0; q < 10; ++q) {
                    float va = (ia < 10) ? mv[a * 10 + ia] : -1e30f;
                    int   xa = (ia < 10) ? mi[a * 10 + ia] : SENT_I;
                    float vb = (ib < 10) ? mv[b * 10 + ib] : -1e30f;
                    int   xb = (ib < 10) ? mi[b * 10 + ib] : SENT_I;
                    bool pa = (va > vb) || (va == vb && xa < xb);
                    if (pa) { ov[q] = va; oi[q] = xa; ia++; }
                    else    { ov[q] = vb; oi[q] = xb; ib++; }
                }
#pragma unroll
                for (int q = 0; q < 10; ++q) { mv[a * 10 + q] = ov[q]; mi[a * 10 + q] = oi[q]; }
            }
            __syncthreads();
        }

        if (tid == 0) {
            for (int q = 0; q < 10; ++q) {
                int p = mi[q];
                bool valid = (p != SENT_I);
                out[128 + k * 10 + q]        = valid ? p  : -1;
                out[1408 + 128 + k * 10 + q] = valid ? gt : -1;
                if (valid) used[p] = 1;
            }
        }
        __syncthreads();
    }
}

// ---------- launch ----------

extern "C" void kernel_launch(void* const* d_in, const int* in_sizes, int n_in,
                              void* d_out, int out_size, void* d_ws, size_t ws_size,
                              hipStream_t stream) {
    const float* pc  = (const float*)d_in[0];
    const float* ps  = (const float*)d_in[1];
    const float* cls = (const float*)d_in[2];
    const float* gc  = (const float*)d_in[4];
    const float* gs  = (const float*)d_in[5];
    const int*   lab = (const int*)d_in[6];

    char* ws = (char*)d_ws;
    float*         costT    = (float*)(ws + 0);                      // 33,554,432 B
    double*        v        = (double*)(ws + 33554432);              //    524,288 B (fallback only)
    double*        shortest = (double*)(ws + 34078720);              //    524,288 B (fallback only)
    int*           path     = (int*)(ws + 34603008);                 //    262,144 B (fallback only)
    int*           row4col  = (int*)(ws + 34865152);                 //    262,144 B (fallback only)
    unsigned char* SC       = (unsigned char*)(ws + 35127296);       //     65,536 B (fallback only)
    unsigned char* used     = (unsigned char*)(ws + 35192832);       //     65,536 B
    int*           ccnt     = (int*)(ws + 35258368);
    unsigned*      cmax     = (unsigned*)(ws + 35258880);
    int*           order    = (int*)(ws + 35259392);
    int*           cidx     = (int*)(ws + 35259904);                 //  6,291,456 B
    float*         cval     = (float*)(ws + 35259904 + (size_t)NGT * CAP * 4); // 6,291,456 B
    // sparse-LSA arrays ALIAS fallback-only v/shortest (fallback re-inits them if it runs)
    float*         segval   = (float*)(ws + 33554432);               //    262,144 B (over v)
    int*           segidx   = (int*)(ws + 33554432 + 262144);        //    262,144 B (over v)
    int*           inVmap   = (int*)(ws + 34078720);                 //    262,144 B (over shortest)
    int*           failFlag = (int*)(ws + 34078720 + 262144);        //          4 B (over shortest)

    int* out = (int*)d_out;

    hipLaunchKernelGGL(k_init, dim3(1), dim3(128), 0, stream, ccnt, cmax);
    hipLaunchKernelGGL(k_cost, dim3(NPRED / 256), dim3(256), 0, stream,
                       pc, ps, cls, gc, gs, lab, costT, ccnt, cmax, cidx, cval);
    hipLaunchKernelGGL(k_sort, dim3(1), dim3(128), 0, stream, cmax, order);
    // 128 rows * 512 segments = 65536 waves, 4 waves/block -> 16384 blocks
    hipLaunchKernelGGL(k_segmin, dim3(16384), dim3(256), 0, stream,
                       costT, segval, segidx, inVmap, failFlag);
    hipLaunchKernelGGL(k_lsa_sparse, dim3(1), dim3(1024), 0, stream,
                       costT, segval, segidx, inVmap, failFlag, used, out);
    hipLaunchKernelGGL(k_lsa_dense, dim3(1), dim3(1024), 0, stream,
                       costT, failFlag, v, shortest, path, row4col, SC, used, out);
    hipLaunchKernelGGL(k_dyn, dim3(1), dim3(256), 0, stream,
                       order, ccnt, cidx, cval, used, out);
}